// Round 2
// baseline (89.731 us; speedup 1.0000x reference)
//
#include <hip/hip_runtime.h>
#include <hip/hip_bf16.h>
#include <stdint.h>

// Problem constants (fixed by the reference)
#define P 2048       // D_STATE
#define HN 64        // D_INPUT
#define L 16384      // kernel_size
#define BN 64        // l-columns per tile
#define NT 4         // tiles per block (column-group covers 256 cols)
#define KQ 4         // K split across blocks (k-quarters)
#define KTWV 4       // kt steps per wave (128 / KQ / 8 waves)
#define HL (HN * L)  // 1048576 floats per partial

typedef __bf16 bf16_t;
typedef bf16_t bf16x8 __attribute__((ext_vector_type(8)));
typedef float f32x16 __attribute__((ext_vector_type(16)));

__device__ __forceinline__ float2 cmul(float2 a, float2 b) {
    return make_float2(a.x * b.x - a.y * b.y, a.x * b.y + a.y * b.x);
}

__device__ __forceinline__ uint32_t packbf(float2 v) {
    union { __hip_bfloat162 v; uint32_t u; } cv;
    cv.v = __float22bfloat162_rn(make_float2(v.x, v.y));
    return cv.u;
}

// ---------------------------------------------------------------------------
// Prep: (a) W in bf16 32x32-MFMA A-fragment order: granule gid =
// ((kt*2+q)*2+mt)*64+lane holds A[m=mt*32+(lane&31)][k-run], p-run =
// kt*16 + q*8 + (lane>>5)*4, elements (W_re, -W_im) pairs (k=2p, 2p+1).
// (b) Tcol[p*32 + lc] = A_p^lc (float2), lc in [0,32) — block-invariant.
// (c) a32[p] = A_p^32, a64[p] = A_p^64 (for base-column derivation/advance).
__global__ void mv_prep(const float* __restrict__ Win,
                        const float* __restrict__ Ain,
                        uint4* __restrict__ wexp,
                        float2* __restrict__ tcol,
                        float2* __restrict__ a32,
                        float2* __restrict__ a64) {
    int gid = blockIdx.x * 256 + threadIdx.x;   // 32768
    {   // wexp
        int lane = gid & 63;
        int mt = (gid >> 6) & 1;
        int q = (gid >> 7) & 1;
        int kt = gid >> 8;
        int m = mt * 32 + (lane & 31);
        int p0 = kt * 16 + q * 8 + (lane >> 5) * 4;
        const float4* wp = (const float4*)(Win + (size_t)(m * P + p0) * 2);
        float4 f0 = wp[0], f1 = wp[1];
        float re[4] = {f0.x, f0.z, f1.x, f1.z};
        float im[4] = {f0.y, f0.w, f1.y, f1.w};
        uint32_t o[4];
#pragma unroll
        for (int j = 0; j < 4; ++j)
            o[j] = packbf(make_float2(re[j], -im[j]));
        wexp[gid] = make_uint4(o[0], o[1], o[2], o[3]);
    }
    {   // Tcol: thread handles p = gid>>4, lc = 2*(gid&15) and lc+1
        int p = gid >> 4;
        int e = gid & 15;                      // lc/2
        float2 a = *(const float2*)(Ain + 2 * p);
        float2 a2 = cmul(a, a);
        float2 r = make_float2(1.f, 0.f);
        float2 sq = a2;
#pragma unroll
        for (int b = 0; b < 4; ++b) {
            if ((e >> b) & 1) r = cmul(r, sq);
            sq = cmul(sq, sq);
        }
        float2 ro = cmul(r, a);
        tcol[(size_t)p * 32 + 2 * e] = r;       // A^(2e)
        tcol[(size_t)p * 32 + 2 * e + 1] = ro;  // A^(2e+1)
        if (e == 15) {
            float2 v32 = cmul(ro, a);           // A^32
            a32[p] = v32;
            a64[p] = cmul(v32, v32);            // A^64
        }
    }
}

// ---------------------------------------------------------------------------
// Main: grid 256 = KQ(4 k-quarters) x 64 column-groups; 512 thr (8 waves).
// Block (kq, cg): kt in [32kq, 32kq+32) (4 kt/wave, held in REGISTERS:
// wexp 64 VGPR + Tcol 64 VGPR), columns [cg*256, cg*256+256) as 4 tiles
// of 64. Tile loop is global-load-free: B-frags = LDS Base x reg Tcol;
// Base advances by A^64 per tile. Partials to ws; mv_reduce sums 4.
__global__ void __launch_bounds__(512, 2) mv_main(
    const float* __restrict__ Ain,
    const uint4* __restrict__ wexp,
    const float2* __restrict__ Tcol,
    const float2* __restrict__ A32,
    const float2* __restrict__ A64,
    float* __restrict__ part) {
    __shared__ __align__(16) float2 Base0[512];      // 4 KB: A_p^(l0)
    __shared__ __align__(16) float2 Base1[512];      // 4 KB: A_p^(l0+32)
    __shared__ float Red[8][2][1024];                // 64 KB

    const int t = threadIdx.x;
    const int kq = blockIdx.x & 3;
    const int cg = blockIdx.x >> 2;
    const int w = t >> 6;
    const int lw = t & 63;
    const int n = lw & 31;         // column within 32-wide tile
    const int kh = lw >> 5;        // k-half of the fragment

    // ---- register-resident K-slice: W fragments + Tcol values ----
    uint4 wreg[KTWV][2][2];        // [kk][mt][q]
    float2 tv[KTWV][8];            // [kk][q*4+j]
    {
        const float2* tc = Tcol + n;
#pragma unroll
        for (int kk = 0; kk < KTWV; ++kk) {
            int kt = kq * 32 + w * 4 + kk;
#pragma unroll
            for (int q = 0; q < 2; ++q) {
#pragma unroll
                for (int mt = 0; mt < 2; ++mt)
                    wreg[kk][mt][q] = wexp[(size_t)(((kt * 2 + q) * 2 + mt) * 64 + lw)];
                int pb = kt * 16 + q * 8 + kh * 4;
#pragma unroll
                for (int jj = 0; jj < 4; ++jj)
                    tv[kk][q * 4 + jj] = tc[(size_t)(pb + jj) * 32];
            }
        }
    }

    // ---- Base build for this block's 512 p's (log-space, e = cg*256) ----
    float2 a64v;
    {
        int p = kq * 512 + t;
        float2 a = ((const float2*)Ain)[p];
        float e = (float)(cg * 256);
        float logr = 0.5f * logf(a.x * a.x + a.y * a.y);
        float th = atan2f(a.y, a.x);
        float mag = expf(e * logr);
        float s, c;
        sincosf(e * th, &s, &c);
        float2 b0 = make_float2(mag * c, mag * s);
        Base0[t] = b0;
        Base1[t] = cmul(b0, A32[p]);
        a64v = A64[p];
    }
    __syncthreads();

    const float4* B0f4 = (const float4*)Base0;
    const float4* B1f4 = (const float4*)Base1;

    // epilogue index helpers (C/D layout m74: col=lane&31,
    // row=(r&3)+8*(r>>2)+4*(lane>>5))
    const int row = t >> 4;                 // 0..31
    const int colb = (t & 15) * 2;          // even column
    const int rr = (row & 3) | ((row >> 3) << 2);
    const int lane0 = colb + ((row >> 2) & 1) * 32;

    // ---- tile loop (global-load-free) ----
    for (int j = 0; j < NT; ++j) {
        f32x16 acc[2][2];
#pragma unroll
        for (int mt = 0; mt < 2; ++mt)
#pragma unroll
            for (int nt = 0; nt < 2; ++nt)
#pragma unroll
                for (int r = 0; r < 16; ++r) acc[mt][nt][r] = 0.f;

#pragma unroll
        for (int kk = 0; kk < KTWV; ++kk) {
#pragma unroll
            for (int q = 0; q < 2; ++q) {
                int bi = (4 * w + kk) * 8 + q * 4 + kh * 2;  // local float4 idx
                float4 c0 = B0f4[bi], c1 = B0f4[bi + 1];
                float4 d0 = B1f4[bi], d1 = B1f4[bi + 1];
                uint32_t f0[4], f1[4];
                {
                    float2 tvv;
                    tvv = tv[kk][q * 4 + 0];
                    f0[0] = packbf(cmul(make_float2(c0.x, c0.y), tvv));
                    f1[0] = packbf(cmul(make_float2(d0.x, d0.y), tvv));
                    tvv = tv[kk][q * 4 + 1];
                    f0[1] = packbf(cmul(make_float2(c0.z, c0.w), tvv));
                    f1[1] = packbf(cmul(make_float2(d0.z, d0.w), tvv));
                    tvv = tv[kk][q * 4 + 2];
                    f0[2] = packbf(cmul(make_float2(c1.x, c1.y), tvv));
                    f1[2] = packbf(cmul(make_float2(d1.x, d1.y), tvv));
                    tvv = tv[kk][q * 4 + 3];
                    f0[3] = packbf(cmul(make_float2(c1.z, c1.w), tvv));
                    f1[3] = packbf(cmul(make_float2(d1.z, d1.w), tvv));
                }
                union { uint4 u; bf16x8 v; } F0, F1, A0, A1;
                F0.u = make_uint4(f0[0], f0[1], f0[2], f0[3]);
                F1.u = make_uint4(f1[0], f1[1], f1[2], f1[3]);
                A0.u = wreg[kk][0][q];
                A1.u = wreg[kk][1][q];
                acc[0][0] = __builtin_amdgcn_mfma_f32_32x32x16_bf16(A0.v, F0.v, acc[0][0], 0, 0, 0);
                acc[1][0] = __builtin_amdgcn_mfma_f32_32x32x16_bf16(A1.v, F0.v, acc[1][0], 0, 0, 0);
                acc[0][1] = __builtin_amdgcn_mfma_f32_32x32x16_bf16(A0.v, F1.v, acc[0][1], 0, 0, 0);
                acc[1][1] = __builtin_amdgcn_mfma_f32_32x32x16_bf16(A1.v, F1.v, acc[1][1], 0, 0, 0);
            }
        }

        // ---- cross-wave reduction: two rounds (mt), 2 sets each ----
#pragma unroll
        for (int mt = 0; mt < 2; ++mt) {
#pragma unroll
            for (int nt = 0; nt < 2; ++nt)
#pragma unroll
                for (int r = 0; r < 16; ++r)
                    Red[w][nt][r * 64 + lw] = acc[mt][nt][r];
            __syncthreads();
#pragma unroll
            for (int nt = 0; nt < 2; ++nt) {
                float sx = 0.f, sy = 0.f;
#pragma unroll
                for (int ww = 0; ww < 8; ++ww) {
                    sx += Red[ww][nt][rr * 64 + lane0];
                    sy += Red[ww][nt][rr * 64 + lane0 + 1];
                }
                *(float2*)(part + (size_t)kq * HL + (size_t)(mt * 32 + row) * L
                           + cg * 256 + j * 64 + nt * 32 + colb) = make_float2(sx, sy);
            }
            __syncthreads();
        }

        // ---- advance Base by A^64 for next tile ----
        if (j < NT - 1) {
            Base0[t] = cmul(Base0[t], a64v);
            Base1[t] = cmul(Base1[t], a64v);
            __syncthreads();
        }
    }
}

// ---------------------------------------------------------------------------
// Reduce: out[i] = sum over 4 k-quarters of partials. 4 MB out, 16 MB in.
__global__ void mv_reduce(const float4* __restrict__ part,
                          float4* __restrict__ out) {
    int i = blockIdx.x * 256 + threadIdx.x;      // 262144 float4
    float4 a = part[i];
    float4 b = part[i + (HL / 4)];
    float4 c = part[i + 2 * (HL / 4)];
    float4 d = part[i + 3 * (HL / 4)];
    out[i] = make_float4(a.x + b.x + c.x + d.x, a.y + b.y + c.y + d.y,
                         a.z + b.z + c.z + d.z, a.w + b.w + c.w + d.w);
}

// ---------------------------------------------------------------------------
extern "C" void kernel_launch(void* const* d_in, const int* in_sizes, int n_in,
                              void* d_out, int out_size, void* d_ws, size_t ws_size,
                              hipStream_t stream) {
    const float* Ain = nullptr;
    const float* Win = nullptr;
    for (int i = 0; i < n_in; ++i) {
        if (in_sizes[i] == 2 * P) Ain = (const float*)d_in[i];
        else if (in_sizes[i] == 2 * HN * P) Win = (const float*)d_in[i];
    }
    if (!Ain) Ain = (const float*)d_in[0];
    if (!Win) Win = (const float*)d_in[1];
    (void)out_size; (void)ws_size;
    uint4* wexp = (uint4*)d_ws;                                  // 512 KB
    float2* tcol = (float2*)((char*)d_ws + 512 * 1024);          // +512 KB
    float2* a32 = (float2*)((char*)d_ws + 1024 * 1024);          // +16 KB
    float2* a64 = (float2*)((char*)d_ws + 1040 * 1024);          // +16 KB
    float* part = (float*)((char*)d_ws + 2 * 1024 * 1024);       // +16 MB
    mv_prep<<<128, 256, 0, stream>>>(Win, Ain, wexp, tcol, a32, a64);
    mv_main<<<256, 512, 0, stream>>>(Ain, wexp, tcol, a32, a64, part);
    mv_reduce<<<1024, 256, 0, stream>>>((const float4*)part, (float4*)d_out);
}

// Round 3
// 88.106 us; speedup vs baseline: 1.0184x; 1.0184x over previous
//
#include <hip/hip_runtime.h>
#include <hip/hip_bf16.h>
#include <stdint.h>

// Problem constants (fixed by the reference)
#define P 2048       // D_STATE
#define HN 64        // D_INPUT
#define L 16384      // kernel_size
#define KTW 16       // kt steps per wave (128 kt / 8 K-split waves)

typedef __bf16 bf16_t;
typedef bf16_t bf16x8 __attribute__((ext_vector_type(8)));
typedef float f32x16 __attribute__((ext_vector_type(16)));

__device__ __forceinline__ float2 cmul(float2 a, float2 b) {
    return make_float2(a.x * b.x - a.y * b.y, a.x * b.y + a.y * b.x);
}

__device__ __forceinline__ uint32_t packbf(float2 v) {
    union { __hip_bfloat162 v; uint32_t u; } cv;
    cv.v = __float22bfloat162_rn(make_float2(v.x, v.y));
    return cv.u;
}

// ---------------------------------------------------------------------------
// Prep: (a) W in bf16 32x32-MFMA A-fragment order: granule gid =
// ((kt*2+q)*2+mt)*64+lane holds A[m=mt*32+(lane&31)][k-run], p-run =
// kt*16 + q*8 + (lane>>5)*4, elements (W_re, -W_im) pairs (k=2p, 2p+1).
// (b) Tcol[p*32 + lc] = A_p^lc (float2), lc in [0,32) — block-invariant.
// (c) a32[p] = A_p^32.
// (d) abase[j*P + p] = A_p^(64j), j in [0,256) — per-block base columns,
//     computed by binary exponentiation (f32-exact to ~30 ulp).
__global__ void mv_prep(const float* __restrict__ Win,
                        const float* __restrict__ Ain,
                        uint4* __restrict__ wexp,
                        float2* __restrict__ tcol,
                        float2* __restrict__ a32,
                        float2* __restrict__ abase) {
    int gid = blockIdx.x * 256 + threadIdx.x;   // 32768
    {   // wexp
        int lane = gid & 63;
        int mt = (gid >> 6) & 1;
        int q = (gid >> 7) & 1;
        int kt = gid >> 8;
        int m = mt * 32 + (lane & 31);
        int p0 = kt * 16 + q * 8 + (lane >> 5) * 4;
        const float4* wp = (const float4*)(Win + (size_t)(m * P + p0) * 2);
        float4 f0 = wp[0], f1 = wp[1];
        float re[4] = {f0.x, f0.z, f1.x, f1.z};
        float im[4] = {f0.y, f0.w, f1.y, f1.w};
        uint32_t o[4];
#pragma unroll
        for (int j = 0; j < 4; ++j)
            o[j] = packbf(make_float2(re[j], -im[j]));
        wexp[gid] = make_uint4(o[0], o[1], o[2], o[3]);
    }
    {   // Tcol: thread handles p = gid>>4, lc = 2*(gid&15) and lc+1
        int p = gid >> 4;
        int e = gid & 15;                      // lc/2
        float2 a = *(const float2*)(Ain + 2 * p);
        float2 a2 = cmul(a, a);
        float2 r = make_float2(1.f, 0.f);
        float2 sq = a2;
#pragma unroll
        for (int b = 0; b < 4; ++b) {
            if ((e >> b) & 1) r = cmul(r, sq);
            sq = cmul(sq, sq);
        }
        float2 ro = cmul(r, a);
        tcol[(size_t)p * 32 + 2 * e] = r;       // A^(2e)
        tcol[(size_t)p * 32 + 2 * e + 1] = ro;  // A^(2e+1)
        if (e == 15) a32[p] = cmul(ro, a);      // A^32
    }
    {   // abase: thread handles p = gid&2047, j in [16*(gid>>11), +16)
        int p = gid & 2047;
        int j16 = gid >> 11;                   // 0..15
        float2 a = *(const float2*)(Ain + 2 * p);
        float2 s = cmul(a, a);                 // A^2
#pragma unroll
        for (int i = 0; i < 5; ++i) s = cmul(s, s);   // A^64
        float2 a64v = s;
        float2 t1k = a64v;
#pragma unroll
        for (int i = 0; i < 4; ++i) t1k = cmul(t1k, t1k);  // A^1024
        float2 r = make_float2(1.f, 0.f);
        float2 sq = t1k;
#pragma unroll
        for (int b = 0; b < 4; ++b) {          // r = (A^1024)^j16
            if ((j16 >> b) & 1) r = cmul(r, sq);
            sq = cmul(sq, sq);
        }
        float2* ab = abase + (size_t)(j16 * 16) * P + p;
#pragma unroll
        for (int i = 0; i < 16; ++i) {
            ab[(size_t)i * P] = r;             // A^(64*(j16*16+i))
            r = cmul(r, a64v);
        }
    }
}

// ---------------------------------------------------------------------------
// Main: grid 256 x 1024 thr (16 waves = 4 waves/SIMD). Block bn covers
// cols [64bn, 64bn+64). Wave w: col-group g = w>>3 (32 cols), K-split
// ks = w&7 (kt in [16ks, 16ks+16)). Wave pairs (0,ks)/(1,ks) read the
// SAME wexp/tcol addresses (L1 reuse). B-frags generated in-register
// (LDS Base_g x reg Tcol). 8-way cross-wave K-reduction per group via
// LDS (Base buffer reused). No global loads except the 1 MB stream.
struct Step {
    uint4 a[2][2];      // [mt][q] wexp A-fragments
    float2 tv[8];       // Tcol values [q*4+j]
};

__global__ void __launch_bounds__(1024, 4) mv_main(
    const uint4* __restrict__ wexp,
    const float2* __restrict__ Tcol,
    const float2* __restrict__ A32,
    const float2* __restrict__ Abase,
    float* __restrict__ out) {
    __shared__ __align__(16) float lds[16384];   // 64 KB: Base0|Base1 -> Red

    const int t = threadIdx.x;
    const int bn = blockIdx.x;
    const int w = t >> 6;
    const int lw = t & 63;
    const int g = w >> 3;          // col-group (0/1)
    const int ks = w & 7;          // K-split
    const int n = lw & 31;         // column within 32-wide tile
    const int kh = lw >> 5;        // k-half of the fragment

    float2* Base0 = (float2*)lds;        // [P] A_p^(64bn)
    float2* Base1 = Base0 + P;           // [P] A_p^(64bn+32)

    {   // Base build: table load + one cmul (no transcendentals)
        float4 ab = ((const float4*)(Abase + (size_t)bn * P))[t];
        float4 a3 = ((const float4*)A32)[t];
        float2 c0 = cmul(make_float2(ab.x, ab.y), make_float2(a3.x, a3.y));
        float2 c1 = cmul(make_float2(ab.z, ab.w), make_float2(a3.z, a3.w));
        ((float4*)Base0)[t] = ab;
        ((float4*)Base1)[t] = make_float4(c0.x, c0.y, c1.x, c1.y);
    }
    __syncthreads();

    const int kt0 = ks * KTW;
    const float2* tc = Tcol + n;
    const float4* Bg = (const float4*)(g ? Base1 : Base0);

    f32x16 acc[2];                 // [mt]
#pragma unroll
    for (int mt = 0; mt < 2; ++mt)
#pragma unroll
        for (int r = 0; r < 16; ++r) acc[mt][r] = 0.f;

    Step s0, s1;

    auto load_step = [&](int kt, Step& s) {
#pragma unroll
        for (int q = 0; q < 2; ++q) {
#pragma unroll
            for (int mt = 0; mt < 2; ++mt)
                s.a[mt][q] = wexp[(size_t)(((kt * 2 + q) * 2 + mt) * 64 + lw)];
            int pb = kt * 16 + q * 8 + kh * 4;
#pragma unroll
            for (int j = 0; j < 4; ++j)
                s.tv[q * 4 + j] = tc[(size_t)(pb + j) * 32];
        }
    };

    auto compute_step = [&](int kt, const Step& s) {
#pragma unroll
        for (int q = 0; q < 2; ++q) {
            int bi = kt * 8 + q * 4 + kh * 2;
            float4 c0 = Bg[bi], c1 = Bg[bi + 1];
            uint32_t f[4];
            f[0] = packbf(cmul(make_float2(c0.x, c0.y), s.tv[q * 4 + 0]));
            f[1] = packbf(cmul(make_float2(c0.z, c0.w), s.tv[q * 4 + 1]));
            f[2] = packbf(cmul(make_float2(c1.x, c1.y), s.tv[q * 4 + 2]));
            f[3] = packbf(cmul(make_float2(c1.z, c1.w), s.tv[q * 4 + 3]));
            union { uint4 u; bf16x8 v; } F, A0, A1;
            F.u = make_uint4(f[0], f[1], f[2], f[3]);
            A0.u = s.a[0][q];
            A1.u = s.a[1][q];
            acc[0] = __builtin_amdgcn_mfma_f32_32x32x16_bf16(A0.v, F.v, acc[0], 0, 0, 0);
            acc[1] = __builtin_amdgcn_mfma_f32_32x32x16_bf16(A1.v, F.v, acc[1], 0, 0, 0);
        }
    };

    load_step(kt0, s0);
#pragma unroll
    for (int i = 0; i < KTW; i += 2) {
        if (i + 1 < KTW) load_step(kt0 + i + 1, s1);
        compute_step(kt0 + i, s0);
        if (i + 2 < KTW) load_step(kt0 + i + 2, s0);
        if (i + 1 < KTW) compute_step(kt0 + i + 1, s1);
    }

    // ---- cross-wave K-reduction per col-group (LDS reused: Base dead) ----
    __syncthreads();
    float* Red = lds;                  // 16 waves x 1024 floats = 64 KB
    // C/D layout (m74): col = lane&31, row = (r&3) + 8*(r>>2) + 4*(lane>>5)
    const int tg = t & 511;
    const int gr = t >> 9;             // output col-group this thread reduces
    const int row = tg >> 4;           // 0..31
    const int colb = (tg & 15) * 2;    // even column
    const int rr = (row & 3) | ((row >> 3) << 2);
    const int lane0 = colb + ((row >> 2) & 1) * 32;

#pragma unroll
    for (int mt = 0; mt < 2; ++mt) {
#pragma unroll
        for (int r = 0; r < 16; ++r)
            Red[(g * 8 + ks) * 1024 + r * 64 + lw] = acc[mt][r];
        __syncthreads();
        float sx = 0.f, sy = 0.f;
#pragma unroll
        for (int ww = 0; ww < 8; ++ww) {
            int base = (gr * 8 + ww) * 1024 + rr * 64 + lane0;
            sx += Red[base];
            sy += Red[base + 1];
        }
        *(float2*)(out + (size_t)(mt * 32 + row) * L + (size_t)bn * 64
                   + gr * 32 + colb) = make_float2(sx, sy);
        __syncthreads();
    }
}

// ---------------------------------------------------------------------------
extern "C" void kernel_launch(void* const* d_in, const int* in_sizes, int n_in,
                              void* d_out, int out_size, void* d_ws, size_t ws_size,
                              hipStream_t stream) {
    const float* Ain = nullptr;
    const float* Win = nullptr;
    for (int i = 0; i < n_in; ++i) {
        if (in_sizes[i] == 2 * P) Ain = (const float*)d_in[i];
        else if (in_sizes[i] == 2 * HN * P) Win = (const float*)d_in[i];
    }
    if (!Ain) Ain = (const float*)d_in[0];
    if (!Win) Win = (const float*)d_in[1];
    (void)out_size; (void)ws_size;
    uint4* wexp = (uint4*)d_ws;                                  // 512 KB
    float2* tcol = (float2*)((char*)d_ws + 512 * 1024);          // +512 KB
    float2* a32 = (float2*)((char*)d_ws + 1024 * 1024);          // +16 KB
    float2* abase = (float2*)((char*)d_ws + 2 * 1024 * 1024);    // +4 MB
    mv_prep<<<128, 256, 0, stream>>>(Win, Ain, wexp, tcol, a32, abase);
    mv_main<<<256, 1024, 0, stream>>>(wexp, tcol, a32, abase, (float*)d_out);
}